// Round 4
// baseline (361.583 us; speedup 1.0000x reference)
//
#include <hip/hip_runtime.h>
#include <hip/hip_bf16.h>

#define B_ 8
#define N_ 1024
#define H_ 8
#define D_ 64

typedef __attribute__((ext_vector_type(8))) short short8;
typedef __attribute__((ext_vector_type(4))) float f32x4;

// ---------------------------------------------------------------------------
// k_colsum: grid (64 bh, 8 chunks), 256 thr.  Round-0 verified body; writes
// per-chunk column-ssq partials (no atomics, no zero kernel) + bf16 w_unit.
// VERIFIED: round 0 (wunit path) + round 2 (cpart path, via output-0 pass).
// ---------------------------------------------------------------------------
__global__ __launch_bounds__(256) void k_colsum(const float* __restrict__ q,
                                                ushort* __restrict__ wunit,
                                                float* __restrict__ cpart) {
    const int bh = blockIdx.x, chunk = blockIdx.y;
    const int b = bh >> 3, h = bh & 7;
    const float* qb = q + (size_t)(b * N_ * H_ + h) * D_;
    __shared__ float red[16][64];
    const int t = threadIdx.x;
    const int ng = t >> 4;          // 16 row-groups
    const int dq = (t & 15) * 4;    // 4 consecutive d per thread
    float cx = 0.f, cy = 0.f, cz = 0.f, cw = 0.f;
    #pragma unroll
    for (int i = 0; i < 8; ++i) {
        const int n = chunk * 128 + ng + i * 16;
        const float4 v = *(const float4*)(qb + (size_t)n * (H_ * D_) + dq);
        cx += v.x * v.x; cy += v.y * v.y; cz += v.z * v.z; cw += v.w * v.w;
        float ss = v.x * v.x + v.y * v.y + v.z * v.z + v.w * v.w;
        ss += __shfl_xor(ss, 1, 16);
        ss += __shfl_xor(ss, 2, 16);
        ss += __shfl_xor(ss, 4, 16);
        ss += __shfl_xor(ss, 8, 16);
        const float invr = 1.0f / fmaxf(sqrtf(ss), 1e-12f);
        __hip_bfloat162 p0 =
            __float22bfloat162_rn(make_float2(v.x * invr, v.y * invr));
        __hip_bfloat162 p1 =
            __float22bfloat162_rn(make_float2(v.z * invr, v.w * invr));
        uint2 pk;
        pk.x = *(unsigned int*)&p0;
        pk.y = *(unsigned int*)&p1;
        *(uint2*)(wunit + ((size_t)bh * N_ + n) * D_ + dq) = pk;
    }
    red[ng][dq + 0] = cx; red[ng][dq + 1] = cy;
    red[ng][dq + 2] = cz; red[ng][dq + 3] = cw;
    __syncthreads();
    if (t < 64) {
        float s = 0.f;
        #pragma unroll
        for (int i = 0; i < 16; ++i) s += red[i][t];
        cpart[((size_t)chunk * 64 + bh) * 64 + t] = s;
    }
}

// ---------------------------------------------------------------------------
// k_epi: grid 256 (b*32+chunk32), 256 thr = 32 n x 8 h.  Fuses energy +
// head-softmax + Pi + dots/Pisum partials.  VERIFIED round 2 (output 0).
// ---------------------------------------------------------------------------
__global__ __launch_bounds__(256) void k_epi(const float* __restrict__ q,
                                             const float* __restrict__ cpart,
                                             const float* __restrict__ temp,
                                             float* __restrict__ Pi,
                                             float* __restrict__ dpart,
                                             float* __restrict__ ppart) {
    const int b = blockIdx.x >> 5, chunk = blockIdx.x & 31;
    const int n0 = chunk * 32;
    const int t = threadIdx.x;
    const int n_l = t >> 3, h = t & 7;
    __shared__ float inv2[8][66];   // padded: lanes span h at fixed d
    __shared__ float dres[8][64];
    __shared__ float psum[8];
    #pragma unroll
    for (int r = 0; r < 2; ++r) {
        const int idx = r * 256 + t, hh = idx >> 6, d = idx & 63;
        float s = 0.f;
        #pragma unroll
        for (int c = 0; c < 8; ++c)
            s += cpart[((size_t)c * 64 + b * 8 + hh) * 64 + d];
        inv2[hh][d] = 1.0f / fmaxf(s, 1e-24f);
        dres[hh][d] = 0.f;
    }
    if (t < 8) psum[t] = 0.f;
    __syncthreads();
    const float* row = q + ((size_t)(b * N_ + n0 + n_l) * H_ + h) * D_;
    float4 s2[16];
    float e = 0.f;
    #pragma unroll
    for (int i = 0; i < 16; ++i) {
        const float4 v = ((const float4*)row)[i];
        s2[i] = make_float4(v.x * v.x, v.y * v.y, v.z * v.z, v.w * v.w);
        e += s2[i].x * inv2[h][4 * i + 0] + s2[i].y * inv2[h][4 * i + 1] +
             s2[i].z * inv2[h][4 * i + 2] + s2[i].w * inv2[h][4 * i + 3];
    }
    e *= temp[h];
    float m = e;
    m = fmaxf(m, __shfl_xor(m, 1, 8));
    m = fmaxf(m, __shfl_xor(m, 2, 8));
    m = fmaxf(m, __shfl_xor(m, 4, 8));
    const float ex = expf(e - m);
    float ssum = ex;
    ssum += __shfl_xor(ssum, 1, 8);
    ssum += __shfl_xor(ssum, 2, 8);
    ssum += __shfl_xor(ssum, 4, 8);
    const float p = ex / ssum;
    Pi[(size_t)(b * 8 + h) * N_ + n0 + n_l] = p;
    atomicAdd(&psum[h], p);
    #pragma unroll
    for (int i = 0; i < 16; ++i) {
        atomicAdd(&dres[h][4 * i + 0], p * s2[i].x);
        atomicAdd(&dres[h][4 * i + 1], p * s2[i].y);
        atomicAdd(&dres[h][4 * i + 2], p * s2[i].z);
        atomicAdd(&dres[h][4 * i + 3], p * s2[i].w);
    }
    __syncthreads();
    const size_t base = (size_t)(b * 32 + chunk) * 512;
    dpart[base + t] = ((const float*)dres)[t];
    dpart[base + 256 + t] = ((const float*)dres)[256 + t];
    if (t < 8) ppart[(size_t)(b * 32 + chunk) * 8 + t] = psum[t];
}

// ---------------------------------------------------------------------------
// k_out2: grid (64 bh, 4 chunks), 256 thr.  Sums dots/Pisum partials ->
// attnv in LDS, then fused outw.  VERIFIED round 2 (output 0).
// ---------------------------------------------------------------------------
__global__ __launch_bounds__(256) void k_out2(const float* __restrict__ q,
                                              const float* __restrict__ Pi,
                                              const float* __restrict__ dpart,
                                              const float* __restrict__ ppart,
                                              float* __restrict__ out0) {
    const int bh = blockIdx.x, nc = blockIdx.y;
    const int b = bh >> 3, h = bh & 7;
    __shared__ float av[64];
    const int t = threadIdx.x;
    if (t < 64) {
        float ds = 0.f, S = 0.f;
        #pragma unroll
        for (int c = 0; c < 32; ++c) {
            ds += dpart[((size_t)(b * 32 + c) * 8 + h) * 64 + t];
            S += ppart[(size_t)(b * 32 + c) * 8 + h];
        }
        av[t] = 1.0f / (1.0f + ds / (S + 1e-8f));
    }
    __syncthreads();
    const int n = nc * 256 + t;
    const float p = -Pi[(size_t)bh * N_ + n];
    const float4* row =
        (const float4*)(q + ((size_t)(b * N_ + n) * H_ + h) * D_);
    f32x4* orow = (f32x4*)(out0 + ((size_t)(b * N_ + n) * H_ + h) * D_);
    #pragma unroll
    for (int i = 0; i < 16; ++i) {
        const float4 v = row[i];
        f32x4 o = {v.x * p * av[4 * i + 0], v.y * p * av[4 * i + 1],
                   v.z * p * av[4 * i + 2], v.w * p * av[4 * i + 3]};
        __builtin_nontemporal_store(o, orow + i);
    }
}

// ---------------------------------------------------------------------------
// k_gram: round-0 VERIFIED kernel, verbatim except the tile decode swap:
// tm = bx&7 (was tn), tn = bx>>3 (was tm).  Consecutively-dispatched blocks
// now share output rows and walk adjacent 128-col (512 B) strips, so
// concurrent blocks cover contiguous 4 KB row spans and L2 can merge the
// 512 B store segments.  Decode is bijective either way (no correctness
// impact).  36 KB LDS -> 4 blocks/CU: loads/MFMA/stores of different blocks
// overlap (no phase-drain serialization).
// ---------------------------------------------------------------------------
__global__ __launch_bounds__(256) void k_gram(const ushort* __restrict__ wunit,
                                              float* __restrict__ out1) {
    const int bh = blockIdx.y;
    const int b = bh >> 3, h = bh & 7;
    const int tm = blockIdx.x & 7, tn = blockIdx.x >> 3;  // <-- only change
    __shared__ __align__(16) char smem[36864];
    ushort(*lA)[72] = (ushort(*)[72])smem;
    ushort(*lB)[72] = (ushort(*)[72])(smem + 18432);
    float* stg = (float*)smem;  // reused after MFMA phase
    const int t = threadIdx.x;
    const ushort* Ub = wunit + (size_t)bh * N_ * D_;

    {
        const uint4* gA = (const uint4*)(Ub + (size_t)tn * 128 * D_);
        const uint4* gB = (const uint4*)(Ub + (size_t)tm * 128 * D_);
        #pragma unroll
        for (int c = 0; c < 4; ++c) {
            const int idx = t + c * 256;
            const int row = idx >> 3, col8 = (idx & 7) * 8;
            *(uint4*)&lA[row][col8] = gA[idx];
            *(uint4*)&lB[row][col8] = gB[idx];
        }
    }
    __syncthreads();

    const int wave = t >> 6, lane = t & 63;
    const int rbase = wave * 32;
    const int arow = lane & 15;
    const int kq = (lane >> 4) * 8;

    f32x4 acc[2][8];
    #pragma unroll
    for (int i = 0; i < 2; ++i)
        #pragma unroll
        for (int j = 0; j < 8; ++j) acc[i][j] = (f32x4){0.f, 0.f, 0.f, 0.f};

    #pragma unroll
    for (int kk = 0; kk < 2; ++kk) {
        const int ko = kk * 32 + kq;
        const short8 a0 = *(const short8*)&lA[rbase + arow][ko];
        const short8 a1 = *(const short8*)&lA[rbase + 16 + arow][ko];
        #pragma unroll
        for (int tc = 0; tc < 8; ++tc) {
            const short8 bfr = *(const short8*)&lB[tc * 16 + arow][ko];
            acc[0][tc] = __builtin_amdgcn_mfma_f32_16x16x32_bf16(
                a0, bfr, acc[0][tc], 0, 0, 0);
            acc[1][tc] = __builtin_amdgcn_mfma_f32_16x16x32_bf16(
                a1, bfr, acc[1][tc], 0, 0, 0);
        }
    }
    __syncthreads();  // all waves done reading lA/lB before staging overwrite

    // Staging: rows padded to 132 floats (2-way bank aliasing on writes: free).
    float* ms = stg + wave * 2112;          // 16*132 floats per wave
    const int col = lane & 15, rq = (lane >> 4) * 4;
    #pragma unroll
    for (int tr = 0; tr < 2; ++tr) {
        #pragma unroll
        for (int tc = 0; tc < 8; ++tc)
            #pragma unroll
            for (int r = 0; r < 4; ++r)
                ms[(rq + r) * 132 + tc * 16 + col] =
                    (acc[tr][tc][r] + 1.0f) * 0.5f;
        // in-wave DS ordering guarantees write->read; lgkmcnt handles data dep
        #pragma unroll
        for (int i = 0; i < 8; ++i) {
            const int f = i * 64 + lane;
            const int r2 = f >> 5, c2 = f & 31;
            const float4 v = *(const float4*)&ms[r2 * 132 + c2 * 4];
            const int n = tn * 128 + wave * 32 + tr * 16 + r2;
            const int m = tm * 128 + c2 * 4;
            *(float4*)&out1[((size_t)(b * N_ + n) * H_ + h) * N_ + m] = v;
        }
    }
}

// ---------------------------------------------------------------------------
extern "C" void kernel_launch(void* const* d_in, const int* in_sizes, int n_in,
                              void* d_out, int out_size, void* d_ws,
                              size_t ws_size, hipStream_t stream) {
    const float* q = (const float*)d_in[0];     // [B, N, H, D] fp32
    const float* temp = (const float*)d_in[1];  // [H] fp32
    float* out0 = (float*)d_out;                       // [B,N,H,D]
    float* out1 = out0 + (size_t)B_ * N_ * H_ * D_;    // [B,N,H,N]

    char* ws = (char*)d_ws;
    ushort* wunit = (ushort*)ws;                 // 8,388,608 B
    float* Pi     = (float*)(ws + 8388608);      //   262,144 B
    float* cpart  = (float*)(ws + 8650752);      //   131,072 B (8 x 64bh x 64)
    float* dpart  = (float*)(ws + 8781824);      //   524,288 B (8b x 32c x 512)
    float* ppart  = (float*)(ws + 9306112);      //     8,192 B (8b x 32c x 8)

    k_colsum<<<dim3(64, 8), 256, 0, stream>>>(q, wunit, cpart);
    k_epi<<<256, 256, 0, stream>>>(q, cpart, temp, Pi, dpart, ppart);
    k_out2<<<dim3(64, 4), 256, 0, stream>>>(q, Pi, dpart, ppart, out0);
    k_gram<<<dim3(64, 64), 256, 0, stream>>>(wunit, out1);
}

// Round 6
// 352.191 us; speedup vs baseline: 1.0267x; 1.0267x over previous
//
#include <hip/hip_runtime.h>
#include <hip/hip_bf16.h>

#define B_ 8
#define N_ 1024
#define H_ 8
#define D_ 64

typedef __attribute__((ext_vector_type(8))) short short8;
typedef __attribute__((ext_vector_type(4))) float f32x4;

// ---------------------------------------------------------------------------
// k_colsum: grid (64 bh, 8 chunks), 256 thr.  VERIFIED rounds 0/2/4.
// ---------------------------------------------------------------------------
__global__ __launch_bounds__(256) void k_colsum(const float* __restrict__ q,
                                                ushort* __restrict__ wunit,
                                                float* __restrict__ cpart) {
    const int bh = blockIdx.x, chunk = blockIdx.y;
    const int b = bh >> 3, h = bh & 7;
    const float* qb = q + (size_t)(b * N_ * H_ + h) * D_;
    __shared__ float red[16][64];
    const int t = threadIdx.x;
    const int ng = t >> 4;          // 16 row-groups
    const int dq = (t & 15) * 4;    // 4 consecutive d per thread
    float cx = 0.f, cy = 0.f, cz = 0.f, cw = 0.f;
    #pragma unroll
    for (int i = 0; i < 8; ++i) {
        const int n = chunk * 128 + ng + i * 16;
        const float4 v = *(const float4*)(qb + (size_t)n * (H_ * D_) + dq);
        cx += v.x * v.x; cy += v.y * v.y; cz += v.z * v.z; cw += v.w * v.w;
        float ss = v.x * v.x + v.y * v.y + v.z * v.z + v.w * v.w;
        ss += __shfl_xor(ss, 1, 16);
        ss += __shfl_xor(ss, 2, 16);
        ss += __shfl_xor(ss, 4, 16);
        ss += __shfl_xor(ss, 8, 16);
        const float invr = 1.0f / fmaxf(sqrtf(ss), 1e-12f);
        __hip_bfloat162 p0 =
            __float22bfloat162_rn(make_float2(v.x * invr, v.y * invr));
        __hip_bfloat162 p1 =
            __float22bfloat162_rn(make_float2(v.z * invr, v.w * invr));
        uint2 pk;
        pk.x = *(unsigned int*)&p0;
        pk.y = *(unsigned int*)&p1;
        *(uint2*)(wunit + ((size_t)bh * N_ + n) * D_ + dq) = pk;
    }
    red[ng][dq + 0] = cx; red[ng][dq + 1] = cy;
    red[ng][dq + 2] = cz; red[ng][dq + 3] = cw;
    __syncthreads();
    if (t < 64) {
        float s = 0.f;
        #pragma unroll
        for (int i = 0; i < 16; ++i) s += red[i][t];
        cpart[((size_t)chunk * 64 + bh) * 64 + t] = s;
    }
}

// ---------------------------------------------------------------------------
// k_epi: grid 256, 256 thr = 32 n x 8 h.  VERIFIED rounds 2/4.
// ---------------------------------------------------------------------------
__global__ __launch_bounds__(256) void k_epi(const float* __restrict__ q,
                                             const float* __restrict__ cpart,
                                             const float* __restrict__ temp,
                                             float* __restrict__ Pi,
                                             float* __restrict__ dpart,
                                             float* __restrict__ ppart) {
    const int b = blockIdx.x >> 5, chunk = blockIdx.x & 31;
    const int n0 = chunk * 32;
    const int t = threadIdx.x;
    const int n_l = t >> 3, h = t & 7;
    __shared__ float inv2[8][66];   // padded: lanes span h at fixed d
    __shared__ float dres[8][64];
    __shared__ float psum[8];
    #pragma unroll
    for (int r = 0; r < 2; ++r) {
        const int idx = r * 256 + t, hh = idx >> 6, d = idx & 63;
        float s = 0.f;
        #pragma unroll
        for (int c = 0; c < 8; ++c)
            s += cpart[((size_t)c * 64 + b * 8 + hh) * 64 + d];
        inv2[hh][d] = 1.0f / fmaxf(s, 1e-24f);
        dres[hh][d] = 0.f;
    }
    if (t < 8) psum[t] = 0.f;
    __syncthreads();
    const float* row = q + ((size_t)(b * N_ + n0 + n_l) * H_ + h) * D_;
    float4 s2[16];
    float e = 0.f;
    #pragma unroll
    for (int i = 0; i < 16; ++i) {
        const float4 v = ((const float4*)row)[i];
        s2[i] = make_float4(v.x * v.x, v.y * v.y, v.z * v.z, v.w * v.w);
        e += s2[i].x * inv2[h][4 * i + 0] + s2[i].y * inv2[h][4 * i + 1] +
             s2[i].z * inv2[h][4 * i + 2] + s2[i].w * inv2[h][4 * i + 3];
    }
    e *= temp[h];
    float m = e;
    m = fmaxf(m, __shfl_xor(m, 1, 8));
    m = fmaxf(m, __shfl_xor(m, 2, 8));
    m = fmaxf(m, __shfl_xor(m, 4, 8));
    const float ex = expf(e - m);
    float ssum = ex;
    ssum += __shfl_xor(ssum, 1, 8);
    ssum += __shfl_xor(ssum, 2, 8);
    ssum += __shfl_xor(ssum, 4, 8);
    const float p = ex / ssum;
    Pi[(size_t)(b * 8 + h) * N_ + n0 + n_l] = p;
    atomicAdd(&psum[h], p);
    #pragma unroll
    for (int i = 0; i < 16; ++i) {
        atomicAdd(&dres[h][4 * i + 0], p * s2[i].x);
        atomicAdd(&dres[h][4 * i + 1], p * s2[i].y);
        atomicAdd(&dres[h][4 * i + 2], p * s2[i].z);
        atomicAdd(&dres[h][4 * i + 3], p * s2[i].w);
    }
    __syncthreads();
    const size_t base = (size_t)(b * 32 + chunk) * 512;
    dpart[base + t] = ((const float*)dres)[t];
    dpart[base + 256 + t] = ((const float*)dres)[256 + t];
    if (t < 8) ppart[(size_t)(b * 32 + chunk) * 8 + t] = psum[t];
}

// ---------------------------------------------------------------------------
// k_out2: grid (64 bh, 4 chunks), 256 thr.  VERIFIED rounds 2/4.
// ---------------------------------------------------------------------------
__global__ __launch_bounds__(256) void k_out2(const float* __restrict__ q,
                                              const float* __restrict__ Pi,
                                              const float* __restrict__ dpart,
                                              const float* __restrict__ ppart,
                                              float* __restrict__ out0) {
    const int bh = blockIdx.x, nc = blockIdx.y;
    const int b = bh >> 3, h = bh & 7;
    __shared__ float av[64];
    const int t = threadIdx.x;
    if (t < 64) {
        float ds = 0.f, S = 0.f;
        #pragma unroll
        for (int c = 0; c < 32; ++c) {
            ds += dpart[((size_t)(b * 32 + c) * 8 + h) * 64 + t];
            S += ppart[(size_t)(b * 32 + c) * 8 + h];
        }
        av[t] = 1.0f / (1.0f + ds / (S + 1e-8f));
    }
    __syncthreads();
    const int n = nc * 256 + t;
    const float p = -Pi[(size_t)bh * N_ + n];
    const float4* row =
        (const float4*)(q + ((size_t)(b * N_ + n) * H_ + h) * D_);
    f32x4* orow = (f32x4*)(out0 + ((size_t)(b * N_ + n) * H_ + h) * D_);
    #pragma unroll
    for (int i = 0; i < 16; ++i) {
        const float4 v = row[i];
        f32x4 o = {v.x * p * av[4 * i + 0], v.y * p * av[4 * i + 1],
                   v.z * p * av[4 * i + 2], v.w * p * av[4 * i + 3]};
        __builtin_nontemporal_store(o, orow + i);
    }
}

// ---------------------------------------------------------------------------
// k_gram: body IDENTICAL to the round-0-verified kernel; ONLY the block-id
// decode changes.  XCD-dense store mapping: with id%8 -> XCD round-robin,
//   b  = id & 7         -> each XCD owns one batch (1 MB panel set, L2-hot)
//   tm = (id>>3) & 7    -> fastest per-XCD: adjacent 512 B m-strips
//   h  = (id>>6) & 7    -> then head (completes each 32 KB n-row)
//   tn = id >> 9        -> then row-block (walks 4 MB stripes in order)
// The union of one XCD's ~128 co-resident blocks is a CONTIGUOUS 4 MB
// stripe of out1[b]; each XCD streams its own contiguous 32 MB region --
// the same pattern as the 6.2 TB/s fills.  Decode is bijective (3+3+3+3
// bits = 4096).  36 KB LDS -> 4 blocks/CU.
// ---------------------------------------------------------------------------
__global__ __launch_bounds__(256) void k_gram(const ushort* __restrict__ wunit,
                                              float* __restrict__ out1) {
    const int id = blockIdx.x;
    const int b  = id & 7;
    const int tm = (id >> 3) & 7;
    const int h  = (id >> 6) & 7;
    const int tn = id >> 9;
    const int bh = b * 8 + h;
    __shared__ __align__(16) char smem[36864];
    ushort(*lA)[72] = (ushort(*)[72])smem;
    ushort(*lB)[72] = (ushort(*)[72])(smem + 18432);
    float* stg = (float*)smem;  // reused after MFMA phase
    const int t = threadIdx.x;
    const ushort* Ub = wunit + (size_t)bh * N_ * D_;

    {
        const uint4* gA = (const uint4*)(Ub + (size_t)tn * 128 * D_);
        const uint4* gB = (const uint4*)(Ub + (size_t)tm * 128 * D_);
        #pragma unroll
        for (int c = 0; c < 4; ++c) {
            const int idx = t + c * 256;
            const int row = idx >> 3, col8 = (idx & 7) * 8;
            *(uint4*)&lA[row][col8] = gA[idx];
            *(uint4*)&lB[row][col8] = gB[idx];
        }
    }
    __syncthreads();

    const int wave = t >> 6, lane = t & 63;
    const int rbase = wave * 32;
    const int arow = lane & 15;
    const int kq = (lane >> 4) * 8;

    f32x4 acc[2][8];
    #pragma unroll
    for (int i = 0; i < 2; ++i)
        #pragma unroll
        for (int j = 0; j < 8; ++j) acc[i][j] = (f32x4){0.f, 0.f, 0.f, 0.f};

    #pragma unroll
    for (int kk = 0; kk < 2; ++kk) {
        const int ko = kk * 32 + kq;
        const short8 a0 = *(const short8*)&lA[rbase + arow][ko];
        const short8 a1 = *(const short8*)&lA[rbase + 16 + arow][ko];
        #pragma unroll
        for (int tc = 0; tc < 8; ++tc) {
            const short8 bfr = *(const short8*)&lB[tc * 16 + arow][ko];
            acc[0][tc] = __builtin_amdgcn_mfma_f32_16x16x32_bf16(
                a0, bfr, acc[0][tc], 0, 0, 0);
            acc[1][tc] = __builtin_amdgcn_mfma_f32_16x16x32_bf16(
                a1, bfr, acc[1][tc], 0, 0, 0);
        }
    }
    __syncthreads();  // all waves done reading lA/lB before staging overwrite

    // Staging: rows padded to 132 floats (2-way bank aliasing on writes: free).
    float* ms = stg + wave * 2112;          // 16*132 floats per wave
    const int col = lane & 15, rq = (lane >> 4) * 4;
    #pragma unroll
    for (int tr = 0; tr < 2; ++tr) {
        #pragma unroll
        for (int tc = 0; tc < 8; ++tc)
            #pragma unroll
            for (int r = 0; r < 4; ++r)
                ms[(rq + r) * 132 + tc * 16 + col] =
                    (acc[tr][tc][r] + 1.0f) * 0.5f;
        // in-wave DS ordering guarantees write->read; lgkmcnt handles data dep
        #pragma unroll
        for (int i = 0; i < 8; ++i) {
            const int f = i * 64 + lane;
            const int r2 = f >> 5, c2 = f & 31;
            const float4 v = *(const float4*)&ms[r2 * 132 + c2 * 4];
            const int n = tn * 128 + wave * 32 + tr * 16 + r2;
            const int m = tm * 128 + c2 * 4;
            *(float4*)&out1[((size_t)(b * N_ + n) * H_ + h) * N_ + m] = v;
        }
    }
}

// ---------------------------------------------------------------------------
extern "C" void kernel_launch(void* const* d_in, const int* in_sizes, int n_in,
                              void* d_out, int out_size, void* d_ws,
                              size_t ws_size, hipStream_t stream) {
    const float* q = (const float*)d_in[0];     // [B, N, H, D] fp32
    const float* temp = (const float*)d_in[1];  // [H] fp32
    float* out0 = (float*)d_out;                       // [B,N,H,D]
    float* out1 = out0 + (size_t)B_ * N_ * H_ * D_;    // [B,N,H,N]

    char* ws = (char*)d_ws;
    ushort* wunit = (ushort*)ws;                 // 8,388,608 B
    float* Pi     = (float*)(ws + 8388608);      //   262,144 B
    float* cpart  = (float*)(ws + 8650752);      //   131,072 B (8 x 64bh x 64)
    float* dpart  = (float*)(ws + 8781824);      //   524,288 B (8b x 32c x 512)
    float* ppart  = (float*)(ws + 9306112);      //     8,192 B (8b x 32c x 8)

    k_colsum<<<dim3(64, 8), 256, 0, stream>>>(q, wunit, cpart);
    k_epi<<<256, 256, 0, stream>>>(q, cpart, temp, Pi, dpart, ppart);
    k_out2<<<dim3(64, 4), 256, 0, stream>>>(q, Pi, dpart, ppart, out0);
    k_gram<<<4096, 256, 0, stream>>>(wunit, out1);
}